// Round 11
// baseline (117.281 us; speedup 1.0000x reference)
//
#include <hip/hip_runtime.h>

#define N_STFT 1025
#define N_MELS 128
#define BATCH 4
#define TIME 1024
#define MAX_ITER 20

typedef unsigned long long u64;
typedef unsigned int u32;

// Extract per-frequency sparse filterbank structure: each fb row f has at most
// 2 nonzeros at adjacent mel indices (m0, m0+1) — triangular filters.
__global__ void imel_prep(const float* __restrict__ fb, int* __restrict__ m0f,
                          float* __restrict__ w0a, float* __restrict__ w1a) {
  const int w = threadIdx.x >> 6, l = threadIdx.x & 63;
  const int f = blockIdx.x * 4 + w;
  if (f >= N_STFT) return;
  const float* row = fb + (size_t)f * N_MELS;
  const unsigned long long mlo = __ballot(row[l] != 0.0f);
  const unsigned long long mhi = __ballot(row[l + 64] != 0.0f);
  if (l == 0) {
    int m0 = mlo ? __builtin_ctzll(mlo)
                 : (mhi ? 64 + __builtin_ctzll(mhi) : 0);
    if (m0 > N_MELS - 2) m0 = N_MELS - 2;   // all-zero rows (f=0, f=1024) -> w=0
    m0f[f] = m0;
    w0a[f] = row[m0];
    w1a[f] = row[m0 + 1];
  }
}

// pack two rounded fixed-point values into one u64 (no inter-half carry:
// both halves are >=0 and stay < 2^31 during accumulation)
__device__ __forceinline__ u64 pk_rn(float x, float y) {
  return (u64)(u32)__float2int_rn(x) | ((u64)(u32)__float2int_rn(y) << 32);
}

// One WAVE owns TWO full (b,t) rows (r10 structure, 54.5us): 64 lanes x 16
// bins, P[128] u64-packed {rowA,rowB}, wave-private -> no __syncthreads in
// the hot loop. Occupancy is structurally capped at 2 waves/SIMD (4096 rows /
// 2 per wave / 256 CU), so round 11 adds ILP inside the wave:
//  - scatter prefix chain split 15 -> 3: four independent 4-bin sub-chains
//    per row, each atomically flushing its own (a0,a1) at chunk end (chunk
//    boundaries merge via the atomic regardless of the adv pattern);
//  - gather restructured read->zero->math: all 16 ds_read2_b64 issue first
//    (collected in regs, ~190 VGPR live, under the (256,2) cap), then the
//    P-zero writes issue behind them (same-wave DS pipe order + may-alias
//    keeps stores after loads), then pure-VALU momentum math.
__global__ __launch_bounds__(256, 2) void imel_main(
    const float* __restrict__ melspec, const float* __restrict__ spec_init,
    const int* __restrict__ m0f, const float* __restrict__ w0a,
    const float* __restrict__ w1a, float* __restrict__ out) {
  __shared__ u64   s_P[4][N_MELS];   // per-wave private, 2 rows packed
  __shared__ float s_mel[8][N_MELS]; // staged mel columns (prologue only)
  __shared__ float s_out[8][1060];   // swizzle-padded: idx = f + (f>>5)

  const int tid = threadIdx.x;
  const int w   = tid >> 6;        // wave 0..3 -> rows t0+2w, t0+2w+1
  const int l   = tid & 63;
  // XCD swizzle: each XCD covers a contiguous (b,t) range
  const int flat = (blockIdx.x & 7) * 64 + (blockIdx.x >> 3);
  const int b   = flat >> 7;          // 128 flats per batch
  const int t0  = (flat & 127) << 3;  // block covers t0..t0+7
  const int tA  = t0 + 2 * w;

  // ---- stage mel columns coalescedly: s_mel[r][m] = mel[b][m][t0+r] ----
  for (int i = tid; i < 8 * N_MELS; i += 256) {
    const int m = i >> 3, r = i & 7;
    s_mel[r][m] = melspec[((size_t)b * N_MELS + m) * TIME + t0 + r];
  }
  __syncthreads();

  const float SCALE  = 16777216.0f;              // 2^24 fixed point
  const float GRAD_N = -2.0f / (BATCH * TIME);   // true grad prefactor
  const float C2 = (2.0f / (BATCH * TIME)) * 3.5527136788005009e-15f; // *2^-48

  // per-lane static structure, f = 16*l + k  (f=1024: zero fb row -> copy)
  float rsA[16], rsB[16], rbA[16], rbB[16];
  float rw0[16], rw1[16], ccA[16], ccB[16];
  int rm[16];

  const float* srowA = spec_init + (size_t)(b * TIME + tA) * N_STFT;
  const float* srowB = srowA + N_STFT;
  const float* melA = &s_mel[2 * w][0];
  const float* melB = &s_mel[2 * w + 1][0];
#pragma unroll
  for (int k = 0; k < 16; ++k) {
    const int f = (l << 4) + k;
    rsA[k] = srowA[f];
    rsB[k] = srowB[f];
    const int m = m0f[f];
    rm[k] = m;
    const float w0 = w0a[f], w1 = w1a[f];
    rw0[k] = w0 * SCALE;
    rw1[k] = w1 * SCALE;
    ccA[k] = GRAD_N * fmaf(melA[m], w0, melA[m + 1] * w1);
    ccB[k] = GRAD_N * fmaf(melB[m], w0, melB[m + 1] * w1);
    rbA[k] = 0.f;
    rbB[k] = 0.f;
  }
  const float rtA = (l == 63) ? srowA[1024] : 0.f;
  const float rtB = (l == 63) ? srowB[1024] : 0.f;

  // loop-invariant advance flags (m0 monotone, step <= 1 per bin)
  bool adv[16];
  adv[0] = false;
#pragma unroll
  for (int k = 1; k < 16; ++k) adv[k] = (rm[k] != rm[k - 1]);

  u64* __restrict__ Pw = &s_P[w][0];
  Pw[l] = 0ULL;
  Pw[l + 64] = 0ULL;
  // wave-private P: no block barrier anywhere in the hot loop

  for (int it = 0; it < MAX_ITER; ++it) {
    // ---- forward: 4 independent 4-bin sub-chains per row (chain depth 3,
    //      8 parallel chains incl. rows A/B), atomic merge at chunk ends ----
#pragma unroll
    for (int c4 = 0; c4 < 4; ++c4) {
      const int k0 = c4 * 4;
      float a0A = rsA[k0] * rw0[k0], a1A = rsA[k0] * rw1[k0];
      float a0B = rsB[k0] * rw0[k0], a1B = rsB[k0] * rw1[k0];
#pragma unroll
      for (int j = 1; j < 4; ++j) {
        const int k = k0 + j;
        if (adv[k]) atomicAdd(&Pw[rm[k - 1]], pk_rn(a0A, a0B));
        const float n0A = (adv[k] ? a1A : a0A) + rsA[k] * rw0[k];
        a1A = (adv[k] ? 0.f : a1A) + rsA[k] * rw1[k];
        a0A = n0A;
        const float n0B = (adv[k] ? a1B : a0B) + rsB[k] * rw0[k];
        a1B = (adv[k] ? 0.f : a1B) + rsB[k] * rw1[k];
        a0B = n0B;
      }
      atomicAdd(&Pw[rm[k0 + 3]],     pk_rn(a0A, a0B));
      atomicAdd(&Pw[rm[k0 + 3] + 1], pk_rn(a1A, a1B));
    }
    __builtin_amdgcn_wave_barrier();   // keep reads after atomics
    // ---- backward phase 1: issue ALL reads (ds_read2_b64), collect ----
    u64 q0[16], q1[16];
#pragma unroll
    for (int k = 0; k < 16; ++k) {
      q0[k] = Pw[rm[k]];
      q1[k] = Pw[rm[k] + 1];
    }
    // ---- phase 2: zero P for next iter; stores stay after the loads
    //      (same-wave DS order + may-alias), hidden behind their latency ----
    Pw[l] = 0ULL;
    Pw[l + 64] = 0ULL;
    __builtin_amdgcn_wave_barrier();   // keep math below the zero stores
    // ---- phase 3: pure-VALU momentum + clamp (no DS on critical path) ----
#pragma unroll
    for (int k = 0; k < 16; ++k) {
      const float p0A = (float)(int)(u32)q0[k];
      const float p0B = (float)(int)(u32)(q0[k] >> 32);
      const float p1A = (float)(int)(u32)q1[k];
      const float p1B = (float)(int)(u32)(q1[k] >> 32);
      const float gA = fmaf(fmaf(p1A, rw1[k], p0A * rw0[k]), C2, ccA[k]);
      const float gB = fmaf(fmaf(p1B, rw1[k], p0B * rw0[k]), C2, ccB[k]);
      rbA[k] = fmaf(0.9f, rbA[k], gA);
      rbB[k] = fmaf(0.9f, rbB[k], gB);
      rsA[k] = fmaxf(fmaf(-0.3f, rbA[k], rsA[k]), 0.f);
      rsB[k] = fmaxf(fmaf(-0.3f, rbB[k], rsB[k]), 0.f);
    }
  }

  // ---- epilogue: transpose (f-major regs) -> (B, F, T) via swizzled LDS ----
#pragma unroll
  for (int k = 0; k < 16; ++k) {
    const int f = (l << 4) + k;
    s_out[2 * w][f + (f >> 5)]     = rsA[k];
    s_out[2 * w + 1][f + (f >> 5)] = rsB[k];
  }
  if (l == 63) {
    s_out[2 * w][1056]     = rtA;    // f=1024 -> 1024 + (1024>>5)
    s_out[2 * w + 1][1056] = rtB;
  }
  __syncthreads();

  const int tl = tid & 7;    // t offset within the block's 8 rows
  const int fg = tid >> 3;   // 32 f phases
  float* obase = out + (size_t)b * N_STFT * TIME + t0 + tl;
  for (int f = fg; f < N_STFT; f += 32) {
    obase[(size_t)f * TIME] = s_out[tl][f + (f >> 5)];
  }
}

extern "C" void kernel_launch(void* const* d_in, const int* in_sizes, int n_in,
                              void* d_out, int out_size, void* d_ws, size_t ws_size,
                              hipStream_t stream) {
  const float* melspec = (const float*)d_in[0];
  const float* spec_init = (const float*)d_in[1];
  const float* fb = (const float*)d_in[2];
  float* out = (float*)d_out;

  int* m0f = (int*)d_ws;                          // 1025 ints
  float* w0a = (float*)((char*)d_ws + 5120);      // 1025 floats
  float* w1a = (float*)((char*)d_ws + 10240);     // 1025 floats

  imel_prep<<<dim3(257), dim3(256), 0, stream>>>(fb, m0f, w0a, w1a);
  imel_main<<<dim3(512), dim3(256), 0, stream>>>(melspec, spec_init, m0f, w0a, w1a, out);
}